// Round 12
// baseline (718.961 us; speedup 1.0000x reference)
//
#include <hip/hip_runtime.h>
#include <hip/hip_bf16.h>

typedef unsigned short ushort_t;
typedef __attribute__((ext_vector_type(8))) short short8v;
typedef __attribute__((ext_vector_type(4))) float f32x4;
typedef __attribute__((ext_vector_type(4))) int int4v;

#define NN 50000
#define EE 800000
#define RRR 8
#define DD 128
#define NDRUG 4000
#define PPAIR 8192
#define BML 32
#define AFS 1160   // Af row stride in shorts (1152 + 8 pad -> 2-way banks only)

#define XB4   (NN * DD / 4)      // 1,600,000 float4 units
#define WCAT1 (144 * 128 * 8)    // 147,456
#define PREP_T (XB4 + 3 * WCAT1 + 3 * 16384 + 2097152)

__device__ __forceinline__ float bf2f(ushort_t u) {
    unsigned int v = ((unsigned int)u) << 16;
    float f; __builtin_memcpy(&f, &v, 4); return f;
}
__device__ __forceinline__ ushort_t f2bf(float f) {
    unsigned int b; __builtin_memcpy(&b, &f, 4);
    unsigned int r = (b + 0x7FFFu + ((b >> 16) & 1u)) >> 16;
    return (ushort_t)r;
}
__device__ __forceinline__ unsigned int pkbf(float lo, float hi) {
    unsigned int r;
    asm("v_cvt_pk_bf16_f32 %0, %1, %2" : "=v"(r) : "v"(lo), "v"(hi));
    return r;
}

// ---------------- fused prep: xb cvt + Wcat x3 + mW x3 + Wb3 + edge count ----------------
__global__ __launch_bounds__(256) void k_prep(
        const float* __restrict__ x,
        const float* __restrict__ W1, const float* __restrict__ r1,
        const float* __restrict__ W2, const float* __restrict__ r2,
        const float* __restrict__ W3, const float* __restrict__ r3,
        const float* __restrict__ m1W, const float* __restrict__ m2W,
        const float* __restrict__ m3W, const float* __restrict__ bilW,
        const int* __restrict__ ei, const int* __restrict__ et,
        ushort_t* __restrict__ xb,
        ushort_t* __restrict__ Wc1, ushort_t* __restrict__ Wc2, ushort_t* __restrict__ Wc3,
        ushort_t* __restrict__ mo1, ushort_t* __restrict__ mo2, ushort_t* __restrict__ mo3,
        ushort_t* __restrict__ Wb3, int* __restrict__ cnt) {
    int idx = blockIdx.x * 256 + threadIdx.x;
    if (idx < XB4) {
        float4 v = ((const float4*)x)[idx];
        uint2 o;
        o.x = (unsigned int)f2bf(v.x) | ((unsigned int)f2bf(v.y) << 16);
        o.y = (unsigned int)f2bf(v.z) | ((unsigned int)f2bf(v.w) << 16);
        ((uint2*)xb)[idx] = o;
    } else if (idx < XB4 + 3 * WCAT1) {
        int t = idx - XB4;
        int l = t / WCAT1, j = t - l * WCAT1;
        const float* W8   = (l == 0) ? W1 : (l == 1) ? W2 : W3;
        const float* root = (l == 0) ? r1 : (l == 1) ? r2 : r3;
        ushort_t* dst     = (l == 0) ? Wc1 : (l == 1) ? Wc2 : Wc3;
        int e = j & 7, col = (j >> 3) & 127, ko = j >> 10;
        int k = ko * 8 + e, slab = k >> 7, kk = k & 127;
        const float* src = (slab < 8) ? (W8 + slab * 16384) : root;
        dst[j] = f2bf(src[kk * 128 + col]);
    } else if (idx < XB4 + 3 * WCAT1 + 3 * 16384) {
        int t = idx - XB4 - 3 * WCAT1;
        int l = t >> 14, j = t & 16383;
        const float* src = (l == 0) ? m1W : (l == 1) ? m2W : m3W;
        ushort_t* dst    = (l == 0) ? mo1 : (l == 1) ? mo2 : mo3;
        int col = j >> 7, kk = j & 127;
        dst[j] = f2bf(src[kk * 128 + col]);
    } else if (idx < PREP_T) {
        int j = idx - (XB4 + 3 * WCAT1 + 3 * 16384);
        int e = j & 7, o = (j >> 3) & 127, ko = j >> 10;
        Wb3[j] = f2bf(bilW[(size_t)o * 16384 + ko * 8 + e]);
    } else {
        int e = idx - PREP_T;
        if (e < EE) {
            int dst = ei[EE + e];
            atomicAdd(&cnt[dst * RRR + et[e]], 1);
        }
    }
}

// ---------------- dual-quantity multi-block scan (indeg CSR + drug select) ----------------
__global__ __launch_bounds__(1024) void k_scanA(const int* __restrict__ cnt,
                                                const int* __restrict__ ntype,
                                                float* __restrict__ inv,
                                                int* __restrict__ offs,
                                                int* __restrict__ selx,
                                                int* __restrict__ part,
                                                int* __restrict__ part2) {
    __shared__ int w1[16], w2[16];
    int tid = threadIdx.x, wid = tid >> 6, lane = tid & 63;
    int i = blockIdx.x * 1024 + tid;
    int a0 = 0, b0 = 0;
    if (i < NN) {
#pragma unroll
        for (int r = 0; r < RRR; r++) {
            int c = cnt[i * RRR + r];
            a0 += c;
            inv[i * RRR + r] = 1.0f / (float)(c > 0 ? c : 1);
        }
        b0 = (ntype[i] == 0) ? 1 : 0;
    }
    int a = a0, b = b0;
#pragma unroll
    for (int off = 1; off < 64; off <<= 1) {
        int ua = __shfl_up(a, off);
        int ub = __shfl_up(b, off);
        if (lane >= off) { a += ua; b += ub; }
    }
    if (lane == 63) { w1[wid] = a; w2[wid] = b; }
    __syncthreads();
    if (wid == 0) {
        int wa = (lane < 16) ? w1[lane] : 0;
        int wb = (lane < 16) ? w2[lane] : 0;
#pragma unroll
        for (int off = 1; off < 16; off <<= 1) {
            int ua = __shfl_up(wa, off);
            int ub = __shfl_up(wb, off);
            if (lane >= off) { wa += ua; wb += ub; }
        }
        if (lane < 16) { w1[lane] = wa; w2[lane] = wb; }
    }
    __syncthreads();
    if (i < NN) {
        offs[i] = (wid ? w1[wid - 1] : 0) + (a - a0);
        selx[i] = (wid ? w2[wid - 1] : 0) + (b - b0);
    }
    if (tid == 0) { part[blockIdx.x] = w1[15]; part2[blockIdx.x] = w2[15]; }
}

__global__ __launch_bounds__(64) void k_scanB(int* __restrict__ part,
                                              int* __restrict__ part2, int nPart) {
    int tid = threadIdx.x;
    int p0 = (tid < nPart) ? part[tid] : 0;
    int q0 = (tid < nPart) ? part2[tid] : 0;
    int p = p0, q = q0;
#pragma unroll
    for (int off = 1; off < 64; off <<= 1) {
        int u = __shfl_up(p, off);
        int v = __shfl_up(q, off);
        if (tid >= off) { p += u; q += v; }
    }
    if (tid < nPart) { part[tid] = p - p0; part2[tid] = q - q0; }
}

__global__ __launch_bounds__(1024) void k_scanC(int* __restrict__ offs,
                                                const int* __restrict__ selx,
                                                const int* __restrict__ part,
                                                const int* __restrict__ part2,
                                                const int* __restrict__ ntype,
                                                int* __restrict__ cursor,
                                                int* __restrict__ didx) {
    int i = blockIdx.x * 1024 + threadIdx.x;
    if (i < NN) {
        int v = offs[i] + part[blockIdx.x];
        offs[i] = v;
        cursor[i] = v;
        if (ntype[i] == 0) {
            int s = selx[i] + part2[blockIdx.x];
            if (s < NDRUG) didx[s] = i;
        }
    }
    if (i == NN) offs[NN] = EE;
}

__global__ __launch_bounds__(256) void k_scatter(const int* __restrict__ ei,
                                                 const int* __restrict__ et,
                                                 int* __restrict__ cursor,
                                                 int* __restrict__ sorted) {
    int e = blockIdx.x * 256 + threadIdx.x;
    if (e < EE) {
        int dst = ei[EE + e];
        int pos = atomicAdd(&cursor[dst], 1);
        sorted[pos] = ei[e] | (et[e] << 20);
    }
}

// ---------------- fused RGCN layer ----------------
// h_out = relu( [mean_r(h_in) ... , h_in] @ WcatT + bias )
// 512 thr = 8 waves; 32 nodes/block; gather in regs -> LDS bf16 -> MFMA (K=1152)
__global__ __launch_bounds__(512) void k_layer(const ushort_t* __restrict__ hin,
                                               const ushort_t* __restrict__ WcatT,
                                               const float* __restrict__ bias,
                                               const float* __restrict__ inv,
                                               const int* __restrict__ offs,
                                               const int* __restrict__ sorted,
                                               ushort_t* __restrict__ hout) {
    __shared__ short Af[BML * AFS];
    int tid = threadIdx.x;
    int n0 = blockIdx.x * BML;
    int node = tid >> 4, tsub = tid & 15;
    int n = n0 + node;

    float acc[8][8];
#pragma unroll
    for (int r = 0; r < 8; r++)
#pragma unroll
        for (int q = 0; q < 8; q++) acc[r][q] = 0.f;
    short8v hv = {0, 0, 0, 0, 0, 0, 0, 0};

    if (n < NN) {
        hv = ((const short8v*)hin)[(size_t)n * 16 + tsub];
        int e0 = offs[n], e1 = offs[n + 1];
        const int4v* hg = (const int4v*)hin;
        for (int e = e0; e < e1; e++) {
            int pk = sorted[e];
            int src = pk & 0xFFFFF;
            int et = pk >> 20;
            union { int4v v; short s[8]; } u;
            u.v = hg[(size_t)src * 16 + tsub];
            float v[8];
#pragma unroll
            for (int q = 0; q < 8; q++) v[q] = bf2f((ushort_t)u.s[q]);
#define CASE_R(R) case R: _Pragma("unroll") for (int q = 0; q < 8; q++) acc[R][q] += v[q]; break;
            switch (et) {
                CASE_R(0) CASE_R(1) CASE_R(2) CASE_R(3)
                CASE_R(4) CASE_R(5) CASE_R(6) CASE_R(7)
            }
#undef CASE_R
        }
    }
    // flush all 9 slabs (zeros for absent relations / tail rows)
    int nc = (n < NN) ? n : (NN - 1);
#pragma unroll
    for (int slab = 0; slab < 8; slab++) {
        float sc = (n < NN) ? inv[nc * 8 + slab] : 0.f;
        union { unsigned int u[4]; short8v v; } cv;
        cv.u[0] = pkbf(acc[slab][0] * sc, acc[slab][1] * sc);
        cv.u[1] = pkbf(acc[slab][2] * sc, acc[slab][3] * sc);
        cv.u[2] = pkbf(acc[slab][4] * sc, acc[slab][5] * sc);
        cv.u[3] = pkbf(acc[slab][6] * sc, acc[slab][7] * sc);
        *(short8v*)&Af[node * AFS + slab * 128 + tsub * 8] = cv.v;
    }
    *(short8v*)&Af[node * AFS + 1024 + tsub * 8] = hv;
    __syncthreads();

    // MFMA: 8 waves; wave -> (row half, col group of 32)
    int wid = tid >> 6, lane = tid & 63, lo = lane & 15, hi = lane >> 4;
    int rhalf = wid & 1, cgrp = wid >> 1;
    int arow = rhalf * 16 + lo;
    f32x4 a0v = {0.f, 0.f, 0.f, 0.f}, a1v = {0.f, 0.f, 0.f, 0.f};
    const int4v* Bg = (const int4v*)WcatT;
#pragma unroll
    for (int kc = 0; kc < 9; kc++) {
#pragma unroll
        for (int s = 0; s < 4; s++) {
            short8v a = *(const short8v*)&Af[arow * AFS + kc * 128 + s * 32 + hi * 8];
            int ko = kc * 16 + s * 4 + hi;
            union { int4v i; short8v s8; } b0, b1;
            b0.i = Bg[ko * 128 + cgrp * 32 + lo];
            b1.i = Bg[ko * 128 + cgrp * 32 + 16 + lo];
            a0v = __builtin_amdgcn_mfma_f32_16x16x32_bf16(a, b0.s8, a0v, 0, 0, 0);
            a1v = __builtin_amdgcn_mfma_f32_16x16x32_bf16(a, b1.s8, a1v, 0, 0, 0);
        }
    }
#pragma unroll
    for (int q = 0; q < 4; q++) {
        int r = n0 + rhalf * 16 + hi * 4 + q;
        if (r < NN) {
            int c = cgrp * 32 + lo;
            float v0 = fmaxf(a0v[q] + bias[c], 0.f);
            float v1 = fmaxf(a1v[q] + bias[c + 16], 0.f);
            hout[(size_t)r * 128 + c] = f2bf(v0);
            hout[(size_t)r * 128 + c + 16] = f2bf(v1);
        }
    }
}

// ---------------- MFMA GEMM (MLP): C = act(A @ Wt + bias) ----------------
__global__ __launch_bounds__(256) void k_mfma_nn(const ushort_t* __restrict__ A,
                                                 const ushort_t* __restrict__ Wt,
                                                 const float* __restrict__ bias,
                                                 ushort_t* __restrict__ outb,
                                                 float* __restrict__ outf,
                                                 int M, int nMblk, int relu) {
    __shared__ short As[64 * 136];
    __shared__ short Bs[128 * 136];
    int tid = threadIdx.x;
    int mblk = blockIdx.x % nMblk;
    int row0 = mblk * 64;

    const int4v* Ag = (const int4v*)A;
    int4v* AsV = (int4v*)As;
    for (int idx = tid; idx < 1024; idx += 256) {
        int row = idx >> 4, ck = idx & 15;
        int grow = row0 + row;
        int4v v = {0, 0, 0, 0};
        if (grow < M) v = Ag[(size_t)grow * 16 + ck];
        AsV[row * 17 + ck] = v;
    }
    const int4v* Wg = (const int4v*)Wt;
    int4v* BsV = (int4v*)Bs;
    for (int idx = tid; idx < 2048; idx += 256) {
        int col = idx >> 4, ck = idx & 15;
        BsV[col * 17 + ck] = Wg[idx];
    }
    __syncthreads();

    int wid = tid >> 6, lane = tid & 63, lo = lane & 15, hi = lane >> 4;
    int wrow0 = wid * 16;
    f32x4 acc[8];
#pragma unroll
    for (int t = 0; t < 8; t++) acc[t] = (f32x4)(0.f);

#pragma unroll
    for (int s = 0; s < 4; ++s) {
        short8v a = *(const short8v*)&As[(wrow0 + lo) * 136 + s * 32 + hi * 8];
#pragma unroll
        for (int t = 0; t < 8; t++) {
            short8v b = *(const short8v*)&Bs[(t * 16 + lo) * 136 + s * 32 + hi * 8];
            acc[t] = __builtin_amdgcn_mfma_f32_16x16x32_bf16(a, b, acc[t], 0, 0, 0);
        }
    }

#pragma unroll
    for (int t = 0; t < 8; t++) {
        int col = t * 16 + lo;
        float bs = bias ? bias[col] : 0.f;
#pragma unroll
        for (int q = 0; q < 4; q++) {
            int grow = row0 + wrow0 + hi * 4 + q;
            if (grow < M) {
                float v = acc[t][q] + bs;
                if (relu) v = fmaxf(v, 0.f);
                size_t oidx = (size_t)grow * 128 + col;
                if (outb) outb[oidx] = f2bf(v);
                else      outf[oidx] = v;
            }
        }
    }
}

// ---------------- bilinear: 64 pairs/block, 4-way K-split x 2-way pair-split ----------------
// out[p][o] = relu( sum_kk Z[p][kk] * Wb[o][kk] + bb[o] ), Z[p][i*128+j]=fa[p][i]*fb[p][j]
// 512 thr = 8 waves; wave = (ph = wid&1 pair-half of 32, kQ = wid>>1 K-quarter of 4096)
__global__ __launch_bounds__(512) void k_bil(const ushort_t* __restrict__ hb,
                                             const int* __restrict__ didx,
                                             const int* __restrict__ efil,
                                             const ushort_t* __restrict__ Wb,
                                             const float* __restrict__ bilb,
                                             ushort_t* __restrict__ xab) {
    __shared__ __align__(16) char smem[67072];
    __shared__ int pa[64], pb[64];
    float* faT = (float*)smem;             // [i:128][p:65 pad] f32
    float* fbF = (float*)(smem + 33280);   // [p:64][j:132 pad] f32
    int tid = threadIdx.x;
    int p0 = blockIdx.x * 64;

    if (tid < 64) pa[tid] = didx[efil[p0 + tid]];
    else if (tid < 128) pb[tid - 64] = didx[efil[PPAIR + p0 + tid - 64]];
    __syncthreads();

    for (int t = tid; t < 1024; t += 512) {
        int p = t >> 4, c8 = t & 15;
        const int4v* hg = (const int4v*)hb;
        union { int4v v; short s[8]; } ra, rb;
        ra.v = hg[(size_t)pa[p] * 16 + c8];
        rb.v = hg[(size_t)pb[p] * 16 + c8];
        float4* fb4 = (float4*)fbF;
        float4 f0, f1;
        f0.x = bf2f((ushort_t)rb.s[0]); f0.y = bf2f((ushort_t)rb.s[1]);
        f0.z = bf2f((ushort_t)rb.s[2]); f0.w = bf2f((ushort_t)rb.s[3]);
        f1.x = bf2f((ushort_t)rb.s[4]); f1.y = bf2f((ushort_t)rb.s[5]);
        f1.z = bf2f((ushort_t)rb.s[6]); f1.w = bf2f((ushort_t)rb.s[7]);
        fb4[p * 33 + c8 * 2] = f0;
        fb4[p * 33 + c8 * 2 + 1] = f1;
#pragma unroll
        for (int j = 0; j < 8; j++)
            faT[(c8 * 8 + j) * 65 + p] = bf2f((ushort_t)ra.s[j]);
    }
    __syncthreads();

    int wid = tid >> 6, lane = tid & 63, lo = lane & 15, hi = lane >> 4;
    int ph = wid & 1, kQ = wid >> 1;
    const int4v* Wbg = (const int4v*)Wb;
    const float4* fb4 = (const float4*)fbF;

    f32x4 acc0[8], acc1[8];
#pragma unroll
    for (int t = 0; t < 8; t++) { acc0[t] = (f32x4)(0.f); acc1[t] = (f32x4)(0.f); }

    for (int s = 0; s < 128; ++s) {
        int ko = (kQ << 9) + (s << 2) + hi;
        int4v braw[8];
#pragma unroll
        for (int t = 0; t < 8; t++)
            braw[t] = Wbg[ko * 128 + t * 16 + lo];     // 16 lanes contiguous

        int i = (kQ << 5) + (s >> 2);
        int jc4 = ((s & 3) << 3) + (hi << 1);
        short8v afr0, afr1;
#pragma unroll
        for (int mi = 0; mi < 2; ++mi) {
            int prow = (ph << 5) + (mi << 4) + lo;
            float fa = faT[i * 65 + prow];
            float4 f0 = fb4[prow * 33 + jc4];
            float4 f1 = fb4[prow * 33 + jc4 + 1];
            union { unsigned int u[4]; short8v v; } cv;
            cv.u[0] = pkbf(fa * f0.x, fa * f0.y);
            cv.u[1] = pkbf(fa * f0.z, fa * f0.w);
            cv.u[2] = pkbf(fa * f1.x, fa * f1.y);
            cv.u[3] = pkbf(fa * f1.z, fa * f1.w);
            if (mi == 0) afr0 = cv.v; else afr1 = cv.v;
        }
#pragma unroll
        for (int t = 0; t < 8; t++) {
            union { int4v i4; short8v s8; } bb; bb.i4 = braw[t];
            acc0[t] = __builtin_amdgcn_mfma_f32_16x16x32_bf16(afr0, bb.s8, acc0[t], 0, 0, 0);
            acc1[t] = __builtin_amdgcn_mfma_f32_16x16x32_bf16(afr1, bb.s8, acc1[t], 0, 0, 0);
        }
    }
    __syncthreads();   // fa/fb dead; smem becomes reduce buffer (4 x 32p x 128o f32)

    float* redF = (float*)smem;
    // phase A: kQ in {2,3} write region (kQ-2)*2+ph; kQ in {0,1} add matching region
    if (kQ >= 2) {
        float* r = redF + (((kQ - 2) << 1) + ph) * 4096;
#pragma unroll
        for (int t = 0; t < 8; t++)
#pragma unroll
            for (int q = 0; q < 4; q++) {
                r[(hi * 4 + q) * 128 + t * 16 + lo] = acc0[t][q];
                r[(16 + hi * 4 + q) * 128 + t * 16 + lo] = acc1[t][q];
            }
    }
    __syncthreads();
    if (kQ < 2) {
        float* r = redF + ((kQ << 1) + ph) * 4096;
#pragma unroll
        for (int t = 0; t < 8; t++)
#pragma unroll
            for (int q = 0; q < 4; q++) {
                acc0[t][q] += r[(hi * 4 + q) * 128 + t * 16 + lo];
                acc1[t][q] += r[(16 + hi * 4 + q) * 128 + t * 16 + lo];
            }
    }
    __syncthreads();
    // phase B: kQ==1 write region ph; kQ==0 add, bias, relu, store
    if (kQ == 1) {
        float* r = redF + ph * 4096;
#pragma unroll
        for (int t = 0; t < 8; t++)
#pragma unroll
            for (int q = 0; q < 4; q++) {
                r[(hi * 4 + q) * 128 + t * 16 + lo] = acc0[t][q];
                r[(16 + hi * 4 + q) * 128 + t * 16 + lo] = acc1[t][q];
            }
    }
    __syncthreads();
    if (kQ == 0) {
        float* r = redF + ph * 4096;
#pragma unroll
        for (int t = 0; t < 8; t++) {
            int col = t * 16 + lo;
            float bs = bilb[col];
#pragma unroll
            for (int q = 0; q < 4; q++) {
                float s0 = acc0[t][q] + r[(hi * 4 + q) * 128 + col] + bs;
                float s1 = acc1[t][q] + r[(16 + hi * 4 + q) * 128 + col] + bs;
                int pr0 = p0 + (ph << 5) + hi * 4 + q;
                int pr1 = pr0 + 16;
                xab[(size_t)pr0 * 128 + col] = f2bf(fmaxf(s0, 0.f));
                xab[(size_t)pr1 * 128 + col] = f2bf(fmaxf(s1, 0.f));
            }
        }
    }
}

// ---------------- launch ----------------

extern "C" void kernel_launch(void* const* d_in, const int* in_sizes, int n_in,
                              void* d_out, int out_size, void* d_ws, size_t ws_size,
                              hipStream_t stream) {
    const float* x      = (const float*)d_in[0];
    const int*   ei     = (const int*)d_in[1];
    const int*   et     = (const int*)d_in[2];
    const int*   ntype  = (const int*)d_in[3];
    const int*   efil   = (const int*)d_in[4];
    const float* W1 = (const float*)d_in[5];
    const float* r1 = (const float*)d_in[6];
    const float* b1 = (const float*)d_in[7];
    const float* W2 = (const float*)d_in[8];
    const float* r2 = (const float*)d_in[9];
    const float* b2 = (const float*)d_in[10];
    const float* W3 = (const float*)d_in[11];
    const float* r3 = (const float*)d_in[12];
    const float* b3 = (const float*)d_in[13];
    const float* bilW = (const float*)d_in[14];
    const float* bilb = (const float*)d_in[15];
    const float* m1W = (const float*)d_in[16];
    const float* m1b = (const float*)d_in[17];
    const float* m2W = (const float*)d_in[18];
    const float* m2b = (const float*)d_in[19];
    const float* m3W = (const float*)d_in[20];
    const float* m3b = (const float*)d_in[21];
    float* outp = (float*)d_out;

    char* ws = (char*)d_ws;
    size_t off = 0;
    auto alloc = [&](size_t bytes) { size_t c = off; off = (off + bytes + 255) & ~(size_t)255; return c; };

    const int nScanBlk = (NN + 1023) / 1024;   // 49

    size_t oxb   = alloc((size_t)NN * 128 * 2);
    size_t ohA   = alloc((size_t)NN * 128 * 2);
    size_t ohB   = alloc((size_t)NN * 128 * 2);
    size_t oWc1  = alloc((size_t)WCAT1 * 2);
    size_t oWc2  = alloc((size_t)WCAT1 * 2);
    size_t oWc3  = alloc((size_t)WCAT1 * 2);
    size_t omW1  = alloc((size_t)16384 * 2);
    size_t omW2  = alloc((size_t)16384 * 2);
    size_t omW3  = alloc((size_t)16384 * 2);
    size_t oWb   = alloc((size_t)2097152 * 2);
    size_t oxab1 = alloc((size_t)PPAIR * 128 * 2);
    size_t oxab2 = alloc((size_t)PPAIR * 128 * 2);
    size_t ocnt  = alloc((size_t)NN * RRR * sizeof(int));
    size_t odidx = alloc((size_t)NDRUG * sizeof(int));     // adjacent to cnt: merged memset
    size_t oinv  = alloc((size_t)NN * RRR * sizeof(float));
    size_t ooffs = alloc((size_t)(NN + 1) * sizeof(int));
    size_t oselx = alloc((size_t)NN * sizeof(int));
    size_t ocur  = alloc((size_t)NN * sizeof(int));
    size_t opart = alloc((size_t)64 * sizeof(int));
    size_t opart2 = alloc((size_t)64 * sizeof(int));
    size_t osort = alloc((size_t)EE * sizeof(int));

    ushort_t* xb   = (ushort_t*)(ws + oxb);
    ushort_t* hbA  = (ushort_t*)(ws + ohA);
    ushort_t* hbB  = (ushort_t*)(ws + ohB);
    ushort_t* Wc1  = (ushort_t*)(ws + oWc1);
    ushort_t* Wc2  = (ushort_t*)(ws + oWc2);
    ushort_t* Wc3  = (ushort_t*)(ws + oWc3);
    ushort_t* mWt1 = (ushort_t*)(ws + omW1);
    ushort_t* mWt2 = (ushort_t*)(ws + omW2);
    ushort_t* mWt3 = (ushort_t*)(ws + omW3);
    ushort_t* Wb3  = (ushort_t*)(ws + oWb);
    ushort_t* xab1 = (ushort_t*)(ws + oxab1);
    ushort_t* xab2 = (ushort_t*)(ws + oxab2);
    int*      cnt  = (int*)(ws + ocnt);
    int*      didx = (int*)(ws + odidx);
    float*    inv  = (float*)(ws + oinv);
    int*      offs = (int*)(ws + ooffs);
    int*      selx = (int*)(ws + oselx);
    int*      cursor = (int*)(ws + ocur);
    int*      part = (int*)(ws + opart);
    int*      part2 = (int*)(ws + opart2);
    int*      sorted = (int*)(ws + osort);

    // merged memset over adjacent cnt+didx regions
    hipMemsetAsync(cnt, 0, (odidx - ocnt) + (size_t)NDRUG * sizeof(int), stream);

    // fused prep (xb, Wcat x3, mW x3, Wb3, edge count)
    k_prep<<<(PREP_T + EE + 255) / 256, 256, 0, stream>>>(
        x, W1, r1, W2, r2, W3, r3, m1W, m2W, m3W, bilW, ei, et,
        xb, Wc1, Wc2, Wc3, mWt1, mWt2, mWt3, Wb3, cnt);

    // graph setup (dual scan: CSR offsets + drug select)
    k_scanA<<<nScanBlk, 1024, 0, stream>>>(cnt, ntype, inv, offs, selx, part, part2);
    k_scanB<<<1, 64, 0, stream>>>(part, part2, nScanBlk);
    k_scanC<<<nScanBlk + 1, 1024, 0, stream>>>(offs, selx, part, part2, ntype, cursor, didx);
    k_scatter<<<(EE + 255) / 256, 256, 0, stream>>>(ei, et, cursor, sorted);

    const int NBL = (NN + BML - 1) / BML;

    // fused RGCN layers
    k_layer<<<NBL, 512, 0, stream>>>(xb,  Wc1, b1, inv, offs, sorted, hbA);
    k_layer<<<NBL, 512, 0, stream>>>(hbA, Wc2, b2, inv, offs, sorted, hbB);
    k_layer<<<NBL, 512, 0, stream>>>(hbB, Wc3, b3, inv, offs, sorted, hbA);

    // pair head
    k_bil<<<PPAIR / 64, 512, 0, stream>>>(hbA, didx, efil, Wb3, bilb, xab1);
    const int nMblkP = PPAIR / 64;
    k_mfma_nn<<<nMblkP, 256, 0, stream>>>(xab1, mWt1, m1b, xab2, nullptr, PPAIR, nMblkP, 1);
    k_mfma_nn<<<nMblkP, 256, 0, stream>>>(xab2, mWt2, m2b, xab1, nullptr, PPAIR, nMblkP, 1);
    k_mfma_nn<<<nMblkP, 256, 0, stream>>>(xab1, mWt3, m3b, nullptr, outp, PPAIR, nMblkP, 0);
}

// Round 13
// 618.591 us; speedup vs baseline: 1.1623x; 1.1623x over previous
//
#include <hip/hip_runtime.h>
#include <hip/hip_bf16.h>

typedef unsigned short ushort_t;
typedef __attribute__((ext_vector_type(8))) short short8v;
typedef __attribute__((ext_vector_type(4))) float f32x4;
typedef __attribute__((ext_vector_type(4))) int int4v;

#define NN 50000
#define EE 800000
#define RRR 8
#define DD 128
#define NDRUG 4000
#define PPAIR 8192
#define BML 32
#define AFS 1160   // Af row stride in shorts (1152 + 8 pad -> 2-way banks only)

#define XB4   (NN * DD / 4)      // 1,600,000 float4 units
#define WCAT1 (144 * 128 * 8)    // 147,456
#define PREP_T (XB4 + 3 * WCAT1 + 3 * 16384 + 2097152)

__device__ __forceinline__ float bf2f(ushort_t u) {
    unsigned int v = ((unsigned int)u) << 16;
    float f; __builtin_memcpy(&f, &v, 4); return f;
}
__device__ __forceinline__ ushort_t f2bf(float f) {
    unsigned int b; __builtin_memcpy(&b, &f, 4);
    unsigned int r = (b + 0x7FFFu + ((b >> 16) & 1u)) >> 16;
    return (ushort_t)r;
}
__device__ __forceinline__ unsigned int pkbf(float lo, float hi) {
    unsigned int r;
    asm("v_cvt_pk_bf16_f32 %0, %1, %2" : "=v"(r) : "v"(lo), "v"(hi));
    return r;
}

// ---------------- fused prep: xb cvt + Wcat x3 + mW x3 + Wb3 + edge count ----------------
__global__ __launch_bounds__(256) void k_prep(
        const float* __restrict__ x,
        const float* __restrict__ W1, const float* __restrict__ r1,
        const float* __restrict__ W2, const float* __restrict__ r2,
        const float* __restrict__ W3, const float* __restrict__ r3,
        const float* __restrict__ m1W, const float* __restrict__ m2W,
        const float* __restrict__ m3W, const float* __restrict__ bilW,
        const int* __restrict__ ei, const int* __restrict__ et,
        ushort_t* __restrict__ xb,
        ushort_t* __restrict__ Wc1, ushort_t* __restrict__ Wc2, ushort_t* __restrict__ Wc3,
        ushort_t* __restrict__ mo1, ushort_t* __restrict__ mo2, ushort_t* __restrict__ mo3,
        ushort_t* __restrict__ Wb3, int* __restrict__ cnt) {
    int idx = blockIdx.x * 256 + threadIdx.x;
    if (idx < XB4) {
        float4 v = ((const float4*)x)[idx];
        uint2 o;
        o.x = (unsigned int)f2bf(v.x) | ((unsigned int)f2bf(v.y) << 16);
        o.y = (unsigned int)f2bf(v.z) | ((unsigned int)f2bf(v.w) << 16);
        ((uint2*)xb)[idx] = o;
    } else if (idx < XB4 + 3 * WCAT1) {
        int t = idx - XB4;
        int l = t / WCAT1, j = t - l * WCAT1;
        const float* W8   = (l == 0) ? W1 : (l == 1) ? W2 : W3;
        const float* root = (l == 0) ? r1 : (l == 1) ? r2 : r3;
        ushort_t* dst     = (l == 0) ? Wc1 : (l == 1) ? Wc2 : Wc3;
        int e = j & 7, col = (j >> 3) & 127, ko = j >> 10;
        int k = ko * 8 + e, slab = k >> 7, kk = k & 127;
        const float* src = (slab < 8) ? (W8 + slab * 16384) : root;
        dst[j] = f2bf(src[kk * 128 + col]);
    } else if (idx < XB4 + 3 * WCAT1 + 3 * 16384) {
        int t = idx - XB4 - 3 * WCAT1;
        int l = t >> 14, j = t & 16383;
        const float* src = (l == 0) ? m1W : (l == 1) ? m2W : m3W;
        ushort_t* dst    = (l == 0) ? mo1 : (l == 1) ? mo2 : mo3;
        int col = j >> 7, kk = j & 127;
        dst[j] = f2bf(src[kk * 128 + col]);
    } else if (idx < PREP_T) {
        int j = idx - (XB4 + 3 * WCAT1 + 3 * 16384);
        int e = j & 7, o = (j >> 3) & 127, ko = j >> 10;
        Wb3[j] = f2bf(bilW[(size_t)o * 16384 + ko * 8 + e]);
    } else {
        int e = idx - PREP_T;
        if (e < EE) {
            int dst = ei[EE + e];
            atomicAdd(&cnt[dst * RRR + et[e]], 1);
        }
    }
}

// ---------------- dual-quantity multi-block scan (indeg CSR + drug select) ----------------
__global__ __launch_bounds__(1024) void k_scanA(const int* __restrict__ cnt,
                                                const int* __restrict__ ntype,
                                                float* __restrict__ inv,
                                                int* __restrict__ offs,
                                                int* __restrict__ selx,
                                                int* __restrict__ part,
                                                int* __restrict__ part2) {
    __shared__ int w1[16], w2[16];
    int tid = threadIdx.x, wid = tid >> 6, lane = tid & 63;
    int i = blockIdx.x * 1024 + tid;
    int a0 = 0, b0 = 0;
    if (i < NN) {
#pragma unroll
        for (int r = 0; r < RRR; r++) {
            int c = cnt[i * RRR + r];
            a0 += c;
            inv[i * RRR + r] = 1.0f / (float)(c > 0 ? c : 1);
        }
        b0 = (ntype[i] == 0) ? 1 : 0;
    }
    int a = a0, b = b0;
#pragma unroll
    for (int off = 1; off < 64; off <<= 1) {
        int ua = __shfl_up(a, off);
        int ub = __shfl_up(b, off);
        if (lane >= off) { a += ua; b += ub; }
    }
    if (lane == 63) { w1[wid] = a; w2[wid] = b; }
    __syncthreads();
    if (wid == 0) {
        int wa = (lane < 16) ? w1[lane] : 0;
        int wb = (lane < 16) ? w2[lane] : 0;
#pragma unroll
        for (int off = 1; off < 16; off <<= 1) {
            int ua = __shfl_up(wa, off);
            int ub = __shfl_up(wb, off);
            if (lane >= off) { wa += ua; wb += ub; }
        }
        if (lane < 16) { w1[lane] = wa; w2[lane] = wb; }
    }
    __syncthreads();
    if (i < NN) {
        offs[i] = (wid ? w1[wid - 1] : 0) + (a - a0);
        selx[i] = (wid ? w2[wid - 1] : 0) + (b - b0);
    }
    if (tid == 0) { part[blockIdx.x] = w1[15]; part2[blockIdx.x] = w2[15]; }
}

__global__ __launch_bounds__(64) void k_scanB(int* __restrict__ part,
                                              int* __restrict__ part2, int nPart) {
    int tid = threadIdx.x;
    int p0 = (tid < nPart) ? part[tid] : 0;
    int q0 = (tid < nPart) ? part2[tid] : 0;
    int p = p0, q = q0;
#pragma unroll
    for (int off = 1; off < 64; off <<= 1) {
        int u = __shfl_up(p, off);
        int v = __shfl_up(q, off);
        if (tid >= off) { p += u; q += v; }
    }
    if (tid < nPart) { part[tid] = p - p0; part2[tid] = q - q0; }
}

__global__ __launch_bounds__(1024) void k_scanC(int* __restrict__ offs,
                                                const int* __restrict__ selx,
                                                const int* __restrict__ part,
                                                const int* __restrict__ part2,
                                                const int* __restrict__ ntype,
                                                int* __restrict__ cursor,
                                                int* __restrict__ didx) {
    int i = blockIdx.x * 1024 + threadIdx.x;
    if (i < NN) {
        int v = offs[i] + part[blockIdx.x];
        offs[i] = v;
        cursor[i] = v;
        if (ntype[i] == 0) {
            int s = selx[i] + part2[blockIdx.x];
            if (s < NDRUG) didx[s] = i;
        }
    }
    if (i == NN) offs[NN] = EE;
}

__global__ __launch_bounds__(256) void k_scatter(const int* __restrict__ ei,
                                                 const int* __restrict__ et,
                                                 int* __restrict__ cursor,
                                                 int* __restrict__ sorted) {
    int e = blockIdx.x * 256 + threadIdx.x;
    if (e < EE) {
        int dst = ei[EE + e];
        int pos = atomicAdd(&cursor[dst], 1);
        sorted[pos] = ei[e] | (et[e] << 20);
    }
}

// ---------------- fused RGCN layer ----------------
// h_out = relu( [mean_r(h_in) ... , h_in] @ WcatT + bias )
// 512 thr = 8 waves; 32 nodes/block; gather in regs -> LDS bf16 -> MFMA (K=1152)
__global__ __launch_bounds__(512) void k_layer(const ushort_t* __restrict__ hin,
                                               const ushort_t* __restrict__ WcatT,
                                               const float* __restrict__ bias,
                                               const float* __restrict__ inv,
                                               const int* __restrict__ offs,
                                               const int* __restrict__ sorted,
                                               ushort_t* __restrict__ hout) {
    __shared__ short Af[BML * AFS];
    int tid = threadIdx.x;
    int n0 = blockIdx.x * BML;
    int node = tid >> 4, tsub = tid & 15;
    int n = n0 + node;

    float acc[8][8];
#pragma unroll
    for (int r = 0; r < 8; r++)
#pragma unroll
        for (int q = 0; q < 8; q++) acc[r][q] = 0.f;
    short8v hv = {0, 0, 0, 0, 0, 0, 0, 0};

    if (n < NN) {
        hv = ((const short8v*)hin)[(size_t)n * 16 + tsub];
        int e0 = offs[n], e1 = offs[n + 1];
        const int4v* hg = (const int4v*)hin;
        for (int e = e0; e < e1; e++) {
            int pk = sorted[e];
            int src = pk & 0xFFFFF;
            int et = pk >> 20;
            union { int4v v; short s[8]; } u;
            u.v = hg[(size_t)src * 16 + tsub];
            float v[8];
#pragma unroll
            for (int q = 0; q < 8; q++) v[q] = bf2f((ushort_t)u.s[q]);
#define CASE_R(R) case R: _Pragma("unroll") for (int q = 0; q < 8; q++) acc[R][q] += v[q]; break;
            switch (et) {
                CASE_R(0) CASE_R(1) CASE_R(2) CASE_R(3)
                CASE_R(4) CASE_R(5) CASE_R(6) CASE_R(7)
            }
#undef CASE_R
        }
    }
    // flush all 9 slabs (zeros for absent relations / tail rows)
    int nc = (n < NN) ? n : (NN - 1);
#pragma unroll
    for (int slab = 0; slab < 8; slab++) {
        float sc = (n < NN) ? inv[nc * 8 + slab] : 0.f;
        union { unsigned int u[4]; short8v v; } cv;
        cv.u[0] = pkbf(acc[slab][0] * sc, acc[slab][1] * sc);
        cv.u[1] = pkbf(acc[slab][2] * sc, acc[slab][3] * sc);
        cv.u[2] = pkbf(acc[slab][4] * sc, acc[slab][5] * sc);
        cv.u[3] = pkbf(acc[slab][6] * sc, acc[slab][7] * sc);
        *(short8v*)&Af[node * AFS + slab * 128 + tsub * 8] = cv.v;
    }
    *(short8v*)&Af[node * AFS + 1024 + tsub * 8] = hv;
    __syncthreads();

    // MFMA: 8 waves; wave -> (row half, col group of 32)
    int wid = tid >> 6, lane = tid & 63, lo = lane & 15, hi = lane >> 4;
    int rhalf = wid & 1, cgrp = wid >> 1;
    int arow = rhalf * 16 + lo;
    f32x4 a0v = {0.f, 0.f, 0.f, 0.f}, a1v = {0.f, 0.f, 0.f, 0.f};
    const int4v* Bg = (const int4v*)WcatT;
#pragma unroll
    for (int kc = 0; kc < 9; kc++) {
#pragma unroll
        for (int s = 0; s < 4; s++) {
            short8v a = *(const short8v*)&Af[arow * AFS + kc * 128 + s * 32 + hi * 8];
            int ko = kc * 16 + s * 4 + hi;
            union { int4v i; short8v s8; } b0, b1;
            b0.i = Bg[ko * 128 + cgrp * 32 + lo];
            b1.i = Bg[ko * 128 + cgrp * 32 + 16 + lo];
            a0v = __builtin_amdgcn_mfma_f32_16x16x32_bf16(a, b0.s8, a0v, 0, 0, 0);
            a1v = __builtin_amdgcn_mfma_f32_16x16x32_bf16(a, b1.s8, a1v, 0, 0, 0);
        }
    }
#pragma unroll
    for (int q = 0; q < 4; q++) {
        int r = n0 + rhalf * 16 + hi * 4 + q;
        if (r < NN) {
            int c = cgrp * 32 + lo;
            float v0 = fmaxf(a0v[q] + bias[c], 0.f);
            float v1 = fmaxf(a1v[q] + bias[c + 16], 0.f);
            hout[(size_t)r * 128 + c] = f2bf(v0);
            hout[(size_t)r * 128 + c + 16] = f2bf(v1);
        }
    }
}

// ---------------- MFMA GEMM (MLP): C = act(A @ Wt + bias) ----------------
__global__ __launch_bounds__(256) void k_mfma_nn(const ushort_t* __restrict__ A,
                                                 const ushort_t* __restrict__ Wt,
                                                 const float* __restrict__ bias,
                                                 ushort_t* __restrict__ outb,
                                                 float* __restrict__ outf,
                                                 int M, int nMblk, int relu) {
    __shared__ short As[64 * 136];
    __shared__ short Bs[128 * 136];
    int tid = threadIdx.x;
    int mblk = blockIdx.x % nMblk;
    int row0 = mblk * 64;

    const int4v* Ag = (const int4v*)A;
    int4v* AsV = (int4v*)As;
    for (int idx = tid; idx < 1024; idx += 256) {
        int row = idx >> 4, ck = idx & 15;
        int grow = row0 + row;
        int4v v = {0, 0, 0, 0};
        if (grow < M) v = Ag[(size_t)grow * 16 + ck];
        AsV[row * 17 + ck] = v;
    }
    const int4v* Wg = (const int4v*)Wt;
    int4v* BsV = (int4v*)Bs;
    for (int idx = tid; idx < 2048; idx += 256) {
        int col = idx >> 4, ck = idx & 15;
        BsV[col * 17 + ck] = Wg[idx];
    }
    __syncthreads();

    int wid = tid >> 6, lane = tid & 63, lo = lane & 15, hi = lane >> 4;
    int wrow0 = wid * 16;
    f32x4 acc[8];
#pragma unroll
    for (int t = 0; t < 8; t++) acc[t] = (f32x4)(0.f);

#pragma unroll
    for (int s = 0; s < 4; ++s) {
        short8v a = *(const short8v*)&As[(wrow0 + lo) * 136 + s * 32 + hi * 8];
#pragma unroll
        for (int t = 0; t < 8; t++) {
            short8v b = *(const short8v*)&Bs[(t * 16 + lo) * 136 + s * 32 + hi * 8];
            acc[t] = __builtin_amdgcn_mfma_f32_16x16x32_bf16(a, b, acc[t], 0, 0, 0);
        }
    }

#pragma unroll
    for (int t = 0; t < 8; t++) {
        int col = t * 16 + lo;
        float bs = bias ? bias[col] : 0.f;
#pragma unroll
        for (int q = 0; q < 4; q++) {
            int grow = row0 + wrow0 + hi * 4 + q;
            if (grow < M) {
                float v = acc[t][q] + bs;
                if (relu) v = fmaxf(v, 0.f);
                size_t oidx = (size_t)grow * 128 + col;
                if (outb) outb[oidx] = f2bf(v);
                else      outf[oidx] = v;
            }
        }
    }
}

// ---------------- bilinear: 32 pairs/block, K split across 2 blocks (512 blocks) ----------------
// partial[kh][p][o] = sum_{kk in half kh} Z[p][kk] * Wb[o][kk], Z[p][i*128+j]=fa[p][i]*fb[p][j]
__global__ __launch_bounds__(512) void k_bil(const ushort_t* __restrict__ hb,
                                             const int* __restrict__ didx,
                                             const int* __restrict__ efil,
                                             const ushort_t* __restrict__ Wb,
                                             float* __restrict__ partial) {
    __shared__ __align__(16) char smem[65536];
    __shared__ int pa[32], pb[32];
    float* faT = (float*)smem;             // [i:128][33] padded
    float* fbF = (float*)(smem + 16896);   // [p:32][j:132] via float4 stride 33
    int tid = threadIdx.x;
    int pt = blockIdx.x & 255;
    int kh = blockIdx.x >> 8;              // K-half 0/1
    int p0 = pt * 32;

    if (tid < 32) pa[tid] = didx[efil[p0 + tid]];
    else if (tid < 64) pb[tid - 32] = didx[efil[PPAIR + p0 + tid - 32]];
    __syncthreads();

    {
        int p = tid >> 4, c8 = tid & 15;
        const int4v* hg = (const int4v*)hb;
        union { int4v v; short s[8]; } ra, rb;
        ra.v = hg[(size_t)pa[p] * 16 + c8];
        rb.v = hg[(size_t)pb[p] * 16 + c8];
        float4* fb4 = (float4*)fbF;
        float4 f0, f1;
        f0.x = bf2f((ushort_t)rb.s[0]); f0.y = bf2f((ushort_t)rb.s[1]);
        f0.z = bf2f((ushort_t)rb.s[2]); f0.w = bf2f((ushort_t)rb.s[3]);
        f1.x = bf2f((ushort_t)rb.s[4]); f1.y = bf2f((ushort_t)rb.s[5]);
        f1.z = bf2f((ushort_t)rb.s[6]); f1.w = bf2f((ushort_t)rb.s[7]);
        fb4[p * 33 + c8 * 2] = f0;
        fb4[p * 33 + c8 * 2 + 1] = f1;
#pragma unroll
        for (int j = 0; j < 8; j++)
            faT[(c8 * 8 + j) * 33 + p] = bf2f((ushort_t)ra.s[j]);
    }
    __syncthreads();

    int wid = tid >> 6, lane = tid & 63, lo = lane & 15, hi = lane >> 4;
    const int4v* Wbg = (const int4v*)Wb;
    const float4* fb4 = (const float4*)fbF;

    f32x4 acc0[8], acc1[8];
#pragma unroll
    for (int t = 0; t < 8; t++) { acc0[t] = (f32x4)(0.f); acc1[t] = (f32x4)(0.f); }

    for (int s = 0; s < 32; ++s) {
        int ko = (kh << 10) + (wid << 7) + (s << 2) + hi;   // octet index in [kh*1024, ...)
        int4v braw[8];
#pragma unroll
        for (int t = 0; t < 8; t++)
            braw[t] = Wbg[ko * 128 + t * 16 + lo];     // 16 lanes contiguous

        int i = (kh << 6) + (wid << 3) + (s >> 2);     // fa row
        int jc4 = ((s & 3) << 3) + (hi << 1);
        short8v afr0, afr1;
#pragma unroll
        for (int mi = 0; mi < 2; ++mi) {
            int prow = (mi << 4) + lo;
            float fa = faT[i * 33 + prow];
            float4 f0 = fb4[prow * 33 + jc4];
            float4 f1 = fb4[prow * 33 + jc4 + 1];
            union { unsigned int u[4]; short8v v; } cv;
            cv.u[0] = pkbf(fa * f0.x, fa * f0.y);
            cv.u[1] = pkbf(fa * f0.z, fa * f0.w);
            cv.u[2] = pkbf(fa * f1.x, fa * f1.y);
            cv.u[3] = pkbf(fa * f1.z, fa * f1.w);
            if (mi == 0) afr0 = cv.v; else afr1 = cv.v;
        }
#pragma unroll
        for (int t = 0; t < 8; t++) {
            union { int4v i4; short8v s8; } bb; bb.i4 = braw[t];
            acc0[t] = __builtin_amdgcn_mfma_f32_16x16x32_bf16(afr0, bb.s8, acc0[t], 0, 0, 0);
            acc1[t] = __builtin_amdgcn_mfma_f32_16x16x32_bf16(afr1, bb.s8, acc1[t], 0, 0, 0);
        }
    }
    __syncthreads();   // fa/fb dead; smem becomes reduce buffer red[4][32][128]

    float* redF = (float*)smem;
    if (wid >= 4) {
        float* r = redF + (wid - 4) * 4096;
#pragma unroll
        for (int t = 0; t < 8; t++)
#pragma unroll
            for (int q = 0; q < 4; q++) {
                r[(hi * 4 + q) * 128 + t * 16 + lo] = acc0[t][q];
                r[(16 + hi * 4 + q) * 128 + t * 16 + lo] = acc1[t][q];
            }
    }
    __syncthreads();
    if (wid < 4) {
        float* r = redF + wid * 4096;
#pragma unroll
        for (int t = 0; t < 8; t++)
#pragma unroll
            for (int q = 0; q < 4; q++) {
                acc0[t][q] += r[(hi * 4 + q) * 128 + t * 16 + lo];
                acc1[t][q] += r[(16 + hi * 4 + q) * 128 + t * 16 + lo];
            }
    }
    __syncthreads();
    if (wid < 4) {
        float* r = redF + wid * 4096;
#pragma unroll
        for (int t = 0; t < 8; t++)
#pragma unroll
            for (int q = 0; q < 4; q++) {
                r[(hi * 4 + q) * 128 + t * 16 + lo] = acc0[t][q];
                r[(16 + hi * 4 + q) * 128 + t * 16 + lo] = acc1[t][q];
            }
    }
    __syncthreads();
    float* dst = partial + ((size_t)kh * PPAIR + p0) * 128;
    for (int idx = tid; idx < 4096; idx += 512) {
        dst[idx] = redF[idx] + redF[4096 + idx] + redF[8192 + idx] + redF[12288 + idx];
    }
}

// combine the two K-half partials + bias + relu -> bf16
__global__ __launch_bounds__(256) void k_bilred(const float* __restrict__ partial,
                                                const float* __restrict__ bilb,
                                                ushort_t* __restrict__ xab) {
    int idx = blockIdx.x * 256 + threadIdx.x;
    if (idx < PPAIR * 128) {
        float s = partial[idx] + partial[PPAIR * 128 + idx] + bilb[idx & 127];
        xab[idx] = f2bf(fmaxf(s, 0.f));
    }
}

// ---------------- launch ----------------

extern "C" void kernel_launch(void* const* d_in, const int* in_sizes, int n_in,
                              void* d_out, int out_size, void* d_ws, size_t ws_size,
                              hipStream_t stream) {
    const float* x      = (const float*)d_in[0];
    const int*   ei     = (const int*)d_in[1];
    const int*   et     = (const int*)d_in[2];
    const int*   ntype  = (const int*)d_in[3];
    const int*   efil   = (const int*)d_in[4];
    const float* W1 = (const float*)d_in[5];
    const float* r1 = (const float*)d_in[6];
    const float* b1 = (const float*)d_in[7];
    const float* W2 = (const float*)d_in[8];
    const float* r2 = (const float*)d_in[9];
    const float* b2 = (const float*)d_in[10];
    const float* W3 = (const float*)d_in[11];
    const float* r3 = (const float*)d_in[12];
    const float* b3 = (const float*)d_in[13];
    const float* bilW = (const float*)d_in[14];
    const float* bilb = (const float*)d_in[15];
    const float* m1W = (const float*)d_in[16];
    const float* m1b = (const float*)d_in[17];
    const float* m2W = (const float*)d_in[18];
    const float* m2b = (const float*)d_in[19];
    const float* m3W = (const float*)d_in[20];
    const float* m3b = (const float*)d_in[21];
    float* outp = (float*)d_out;

    char* ws = (char*)d_ws;
    size_t off = 0;
    auto alloc = [&](size_t bytes) { size_t c = off; off = (off + bytes + 255) & ~(size_t)255; return c; };

    const int nScanBlk = (NN + 1023) / 1024;   // 49

    size_t oxb   = alloc((size_t)NN * 128 * 2);
    size_t ohA   = alloc((size_t)NN * 128 * 2);
    size_t ohB   = alloc((size_t)NN * 128 * 2);
    size_t oWc1  = alloc((size_t)WCAT1 * 2);
    size_t oWc2  = alloc((size_t)WCAT1 * 2);
    size_t oWc3  = alloc((size_t)WCAT1 * 2);
    size_t omW1  = alloc((size_t)16384 * 2);
    size_t omW2  = alloc((size_t)16384 * 2);
    size_t omW3  = alloc((size_t)16384 * 2);
    size_t oWb   = alloc((size_t)2097152 * 2);
    size_t oxab1 = alloc((size_t)PPAIR * 128 * 2);
    size_t oxab2 = alloc((size_t)PPAIR * 128 * 2);
    size_t opbil = alloc((size_t)2 * PPAIR * 128 * sizeof(float));   // 8 MB partials
    size_t ocnt  = alloc((size_t)NN * RRR * sizeof(int));
    size_t odidx = alloc((size_t)NDRUG * sizeof(int));     // adjacent to cnt: merged memset
    size_t oinv  = alloc((size_t)NN * RRR * sizeof(float));
    size_t ooffs = alloc((size_t)(NN + 1) * sizeof(int));
    size_t oselx = alloc((size_t)NN * sizeof(int));
    size_t ocur  = alloc((size_t)NN * sizeof(int));
    size_t opart = alloc((size_t)64 * sizeof(int));
    size_t opart2 = alloc((size_t)64 * sizeof(int));
    size_t osort = alloc((size_t)EE * sizeof(int));

    ushort_t* xb   = (ushort_t*)(ws + oxb);
    ushort_t* hbA  = (ushort_t*)(ws + ohA);
    ushort_t* hbB  = (ushort_t*)(ws + ohB);
    ushort_t* Wc1  = (ushort_t*)(ws + oWc1);
    ushort_t* Wc2  = (ushort_t*)(ws + oWc2);
    ushort_t* Wc3  = (ushort_t*)(ws + oWc3);
    ushort_t* mWt1 = (ushort_t*)(ws + omW1);
    ushort_t* mWt2 = (ushort_t*)(ws + omW2);
    ushort_t* mWt3 = (ushort_t*)(ws + omW3);
    ushort_t* Wb3  = (ushort_t*)(ws + oWb);
    ushort_t* xab1 = (ushort_t*)(ws + oxab1);
    ushort_t* xab2 = (ushort_t*)(ws + oxab2);
    float*    pbil = (float*)(ws + opbil);
    int*      cnt  = (int*)(ws + ocnt);
    int*      didx = (int*)(ws + odidx);
    float*    inv  = (float*)(ws + oinv);
    int*      offs = (int*)(ws + ooffs);
    int*      selx = (int*)(ws + oselx);
    int*      cursor = (int*)(ws + ocur);
    int*      part = (int*)(ws + opart);
    int*      part2 = (int*)(ws + opart2);
    int*      sorted = (int*)(ws + osort);

    // merged memset over adjacent cnt+didx regions
    hipMemsetAsync(cnt, 0, (odidx - ocnt) + (size_t)NDRUG * sizeof(int), stream);

    // fused prep (xb, Wcat x3, mW x3, Wb3, edge count)
    k_prep<<<(PREP_T + EE + 255) / 256, 256, 0, stream>>>(
        x, W1, r1, W2, r2, W3, r3, m1W, m2W, m3W, bilW, ei, et,
        xb, Wc1, Wc2, Wc3, mWt1, mWt2, mWt3, Wb3, cnt);

    // graph setup (dual scan: CSR offsets + drug select)
    k_scanA<<<nScanBlk, 1024, 0, stream>>>(cnt, ntype, inv, offs, selx, part, part2);
    k_scanB<<<1, 64, 0, stream>>>(part, part2, nScanBlk);
    k_scanC<<<nScanBlk + 1, 1024, 0, stream>>>(offs, selx, part, part2, ntype, cursor, didx);
    k_scatter<<<(EE + 255) / 256, 256, 0, stream>>>(ei, et, cursor, sorted);

    const int NBL = (NN + BML - 1) / BML;

    // fused RGCN layers
    k_layer<<<NBL, 512, 0, stream>>>(xb,  Wc1, b1, inv, offs, sorted, hbA);
    k_layer<<<NBL, 512, 0, stream>>>(hbA, Wc2, b2, inv, offs, sorted, hbB);
    k_layer<<<NBL, 512, 0, stream>>>(hbB, Wc3, b3, inv, offs, sorted, hbA);

    // pair head: 512 blocks (256 pair-tiles x 2 K-halves) -> partials -> combine
    k_bil<<<512, 512, 0, stream>>>(hbA, didx, efil, Wb3, pbil);
    k_bilred<<<(PPAIR * 128 + 255) / 256, 256, 0, stream>>>(pbil, bilb, xab1);
    const int nMblkP = PPAIR / 64;
    k_mfma_nn<<<nMblkP, 256, 0, stream>>>(xab1, mWt1, m1b, xab2, nullptr, PPAIR, nMblkP, 1);
    k_mfma_nn<<<nMblkP, 256, 0, stream>>>(xab2, mWt2, m2b, xab1, nullptr, PPAIR, nMblkP, 1);
    k_mfma_nn<<<nMblkP, 256, 0, stream>>>(xab1, mWt3, m3b, nullptr, outp, PPAIR, nMblkP, 0);
}